// Round 2
// baseline (323.641 us; speedup 1.0000x reference)
//
#include <hip/hip_runtime.h>

// Colorcal: out[b,c,h,w] = image[b,c,h,w] * weight[cam[b],c] + bias[cam[b],c]
// image: [16,3,1024,1024] fp32. Memory-bound: 402.7 MB mandatory traffic
// (201.3 MB read + 201.3 MB write); roofline ~62 us at the 6.55 TB/s the
// harness's own fill kernels demonstrate.
//
// vs R0(318.6us total, kernel ~70-75us inferred): 8 float4 per thread,
// plane-chunked so the cam/weight/bias gather stays wave-uniform (s_loads).
// 8 clustered nontemporal loads per wave (128 B/lane in flight) -> 32 FMA ->
// 8 nontemporal stores. Wave count drops 196,608 -> 24,576; per-wave MLP
// replaces pure-TLP latency hiding. ~48 VGPR keeps the 32-waves/CU band.
// (R1 identical submission hit an infra failure — "container failed twice" —
// so this is the same kernel, re-benched.)
//
// Layout: plane (b*3+c) = 1024*1024 floats = 262,144 f4.
//   ITER=8 f4/thread, BLOCK=256 -> 2048 f4/block -> 128 blocks/plane.
//   grid = 48 planes * 128 = 6144 blocks (24 blocks/CU).

typedef float f4 __attribute__((ext_vector_type(4)));

#define BLOCK 256
#define ITER 8
#define CHUNK (BLOCK * ITER)          // 2048 f4 per block
#define F4_PER_PLANE (1024 * 1024 / 4) // 262144
#define BLOCKS_PER_PLANE (F4_PER_PLANE / CHUNK) // 128

__global__ __launch_bounds__(BLOCK) void colorcal_kernel(
    const f4*    __restrict__ img,
    const int*   __restrict__ cam_idx,
    const float* __restrict__ weight,
    const float* __restrict__ bias,
    f4*          __restrict__ out)
{
    // Wave-uniform scalar chain (blockIdx lives in SGPRs):
    const int plane = blockIdx.x >> 7;        // 0..47  (b*3 + c)
    const int chunk = blockIdx.x & 127;
    const int b     = plane / 3;              // compiler magic-mul, scalar
    const int c     = plane - b * 3;
    const int cam   = cam_idx[b];             // s_load (block-uniform)
    const float s   = weight[cam * 3 + c];    // s_load
    const float t   = bias[cam * 3 + c];      // s_load

    // f4 index; max 12,582,912 < 2^31, byte offset 201 MB < 2^31.
    const int base = plane * F4_PER_PLANE + chunk * CHUNK + (int)threadIdx.x;

    f4 v[ITER];                               // fully static indexing -> VGPRs
    #pragma unroll
    for (int k = 0; k < ITER; ++k)
        v[k] = __builtin_nontemporal_load(&img[base + k * BLOCK]);

    #pragma unroll
    for (int k = 0; k < ITER; ++k) {
        v[k].x = fmaf(v[k].x, s, t);
        v[k].y = fmaf(v[k].y, s, t);
        v[k].z = fmaf(v[k].z, s, t);
        v[k].w = fmaf(v[k].w, s, t);
    }

    #pragma unroll
    for (int k = 0; k < ITER; ++k)
        __builtin_nontemporal_store(v[k], &out[base + k * BLOCK]);
}

extern "C" void kernel_launch(void* const* d_in, const int* in_sizes, int n_in,
                              void* d_out, int out_size, void* d_ws, size_t ws_size,
                              hipStream_t stream)
{
    const f4*    img     = (const f4*)d_in[0];
    const int*   cam_idx = (const int*)d_in[1];
    const float* weight  = (const float*)d_in[2];
    const float* bias    = (const float*)d_in[3];
    f4*          out     = (f4*)d_out;

    const int n_f4  = out_size / 4;           // 12,582,912
    const int grid  = n_f4 / CHUNK;           // 6144 blocks (exact)
    colorcal_kernel<<<grid, BLOCK, 0, stream>>>(img, cam_idx, weight, bias, out);
}